// Round 5
// baseline (1517.027 us; speedup 1.0000x reference)
//
#include <hip/hip_runtime.h>

// ---------------------------------------------------------------------------
// 6-layer GCN. Per layer: h = lrelu?(x) @ W ; y = b + D^-1/2 (A+I) D^-1/2 h
// R4: XCD-pinned slice aggregation with wave-uniform edge walk.
//   hs = dinv (.) h stored slice-major hs[8][N][8]; slice s is processed only
//   by blocks with blockIdx&7==s (round-robin block->XCD => slice L2-resident,
//   3.2 MB < 4 MiB). agg wave = one dst row: 64 lanes = 8 edges x 8 features,
//   edge index wave-uniform (no divergence), cross-edge sum via 3 shfl_xor.
//   Pre-scaled hs removes the per-edge dinv[src] gather.
// d_ws layout: rowptr[N+1] | dinv[N] | ssrc[E] | bufA[64N] | bufB[64N]
// Build temps alias into bufA (released before layer 0 writes bufA).
// ---------------------------------------------------------------------------

__device__ __forceinline__ float readlane_f(float v, int l) {
    union { float f; int i; } u;
    u.f = v;
    u.i = __builtin_amdgcn_readlane(u.i, l);
    return u.f;
}

// --- pass 1: coarse histogram of dst>>7 into NB buckets ---------------------
__global__ __launch_bounds__(256) void bucket_hist(const int* __restrict__ dst,
                                                   int* __restrict__ ghist,
                                                   int E, int NB) {
    __shared__ int h[1024];
    for (int i = threadIdx.x; i < NB; i += 256) h[i] = 0;
    __syncthreads();
    int i = blockIdx.x * blockDim.x + threadIdx.x;
    int stride = gridDim.x * blockDim.x;
    for (; i < E; i += stride) atomicAdd(&h[dst[i] >> 7], 1);
    __syncthreads();
    for (int j = threadIdx.x; j < NB; j += 256) {
        int c = h[j];
        if (c) atomicAdd(&ghist[j], c);
    }
}

// --- pass 2: exclusive scan of bucket counts (single block, 1024 thr) -------
__global__ void bucket_scan(const int* __restrict__ ghist, int* __restrict__ base,
                            int* __restrict__ cursor, int NB, int E) {
    int tid = threadIdx.x, lane = tid & 63, wid = tid >> 6;
    int v = (tid < NB) ? ghist[tid] : 0;
    int incl = v;
#pragma unroll
    for (int off = 1; off < 64; off <<= 1) {
        int t = __shfl_up(incl, off);
        if (lane >= off) incl += t;
    }
    __shared__ int ws[16];
    if (lane == 63) ws[wid] = incl;
    __syncthreads();
    if (tid == 0) {
        int run = 0;
        for (int i = 0; i < 16; ++i) { int t = ws[i]; ws[i] = run; run += t; }
    }
    __syncthreads();
    int excl = ws[wid] + incl - v;
    if (tid < NB) { base[tid] = excl; cursor[tid] = excl; }
    if (tid == 0) base[NB] = E;
}

// --- pass 3: scatter edges into bucket-sorted (bsrc, bdl) -------------------
__global__ __launch_bounds__(256) void bucket_scatter(
    const int* __restrict__ src, const int* __restrict__ dst,
    int* __restrict__ cursor, int* __restrict__ bsrc,
    unsigned char* __restrict__ bdl, int E, int NB) {
    __shared__ int h[1024];
    __shared__ int rb[1024];
    const int CH = 4096;
    for (int c0 = blockIdx.x * CH; c0 < E; c0 += gridDim.x * CH) {
        int cend = c0 + CH < E ? c0 + CH : E;
        for (int j = threadIdx.x; j < NB; j += 256) h[j] = 0;
        __syncthreads();
        for (int i = c0 + threadIdx.x; i < cend; i += 256)
            atomicAdd(&h[dst[i] >> 7], 1);
        __syncthreads();
        for (int j = threadIdx.x; j < NB; j += 256) {
            int c = h[j];
            rb[j] = c ? atomicAdd(&cursor[j], c) : 0;
            h[j] = 0;
        }
        __syncthreads();
        for (int i = c0 + threadIdx.x; i < cend; i += 256) {
            int d = dst[i];
            int b = d >> 7;
            int p = rb[b] + atomicAdd(&h[b], 1);
            bsrc[p] = src[i];
            bdl[p] = (unsigned char)(d & 127);
        }
        __syncthreads();
    }
}

// --- pass 4: per-bucket CSR finalize: rowptr, dinv, ssrc --------------------
__global__ __launch_bounds__(256) void bucket_finalize(
    const int* __restrict__ base, const int* __restrict__ bsrc,
    const unsigned char* __restrict__ bdl, int* __restrict__ rowptr,
    int* __restrict__ ssrc, float* __restrict__ dinv, int N, int NB, int E) {
    __shared__ int cnt[128];
    __shared__ int cur[128];
    __shared__ int w0sum;
    const int tid = threadIdx.x;
    const int lane = tid & 63;
    for (int b = blockIdx.x; b < NB; b += gridDim.x) {
        const int s = base[b], e = base[b + 1];
        const int d0 = b << 7;
        const int w = (N - d0 < 128) ? (N - d0) : 128;
        if (tid < 128) cnt[tid] = 0;
        __syncthreads();
        for (int i = s + tid; i < e; i += 256) atomicAdd(&cnt[bdl[i]], 1);
        __syncthreads();
        int v = (tid < 128) ? cnt[tid] : 0;
        int incl = v;
#pragma unroll
        for (int off = 1; off < 64; off <<= 1) {
            int t = __shfl_up(incl, off);
            if (lane >= off) incl += t;
        }
        if (tid == 63) w0sum = incl;
        __syncthreads();
        int excl = incl - v + ((tid >= 64 && tid < 128) ? w0sum : 0);
        if (tid < 128) cur[tid] = s + excl;
        if (tid < w) {
            rowptr[d0 + tid] = s + excl;
            dinv[d0 + tid] = rsqrtf((float)(v + 1));   // +1 self loop
        }
        __syncthreads();
        for (int i = s + tid; i < e; i += 256) {
            int p = atomicAdd(&cur[bdl[i]], 1);
            ssrc[p] = bsrc[i];
        }
        __syncthreads();
    }
    if (blockIdx.x == 0 && tid == 0) rowptr[N] = E;
}

// --- dense transform + dinv pre-scale:
//   hs[l>>3][row*8+(l&7)] = dinv[row] * sum_k lrelu?(in[row,k]) * W[k,l]
// IN_SLICED: in is slice-major [8][n][8] (pre-activation y); else row-major.
template <int K, bool LRELU, bool IN_SLICED>
__global__ __launch_bounds__(256) void gemm_hs(
    const float* __restrict__ in, const float* __restrict__ W,
    const float* __restrict__ dinv, float* __restrict__ hsS, int n) {
    const int lane = threadIdx.x & 63;
    const int gw = blockIdx.x * (blockDim.x >> 6) + (threadIdx.x >> 6);
    const int nw = gridDim.x * (blockDim.x >> 6);
    const int sl = lane >> 3, f8 = lane & 7;
    const size_t slot = (size_t)sl * n * 8 + f8;   // slice-major slot for lane

    float wreg[K];
#pragma unroll
    for (int k = 0; k < K; ++k) wreg[k] = W[k * 64 + lane];

    for (int row = gw; row < n; row += nw) {
        float xv0, xv1 = 0.f;
        if (IN_SLICED) {
            xv0 = __builtin_nontemporal_load(in + slot + (size_t)row * 8);
        } else {
            xv0 = __builtin_nontemporal_load(in + (size_t)row * K + lane);
            if (K == 128)
                xv1 = __builtin_nontemporal_load(in + (size_t)row * K + 64 + lane);
        }
        if (LRELU) xv0 = xv0 >= 0.f ? xv0 : 0.2f * xv0;
        float a0 = 0.f, a1 = 0.f, a2 = 0.f, a3 = 0.f;
#pragma unroll
        for (int k = 0; k < 64; k += 4) {
            a0 = fmaf(readlane_f(xv0, k + 0), wreg[k + 0], a0);
            a1 = fmaf(readlane_f(xv0, k + 1), wreg[k + 1], a1);
            a2 = fmaf(readlane_f(xv0, k + 2), wreg[k + 2], a2);
            a3 = fmaf(readlane_f(xv0, k + 3), wreg[k + 3], a3);
        }
        if (K == 128) {
#pragma unroll
            for (int k = 0; k < 64; k += 4) {
                a0 = fmaf(readlane_f(xv1, k + 0), wreg[64 + k + 0], a0);
                a1 = fmaf(readlane_f(xv1, k + 1), wreg[64 + k + 1], a1);
                a2 = fmaf(readlane_f(xv1, k + 2), wreg[64 + k + 2], a2);
                a3 = fmaf(readlane_f(xv1, k + 3), wreg[64 + k + 3], a3);
            }
        }
        float acc = (a0 + a1) + (a2 + a3);
        __builtin_nontemporal_store(dinv[row] * acc, hsS + slot + (size_t)row * 8);
    }
}

// --- sliced aggregation: slice = blockIdx&7 (XCD-pinned), one wave per dst
//     row, 64 lanes = 8 edges (g=lane>>3) x 8 features (f=lane&7).
//   y[d,f] = b[f] + dinv[d] * ( hs[d,f] + sum_e hs[src_e, f] )
__global__ __launch_bounds__(256) void csr_agg_sliced8(
    const float* __restrict__ hsS, const int* __restrict__ rowptr,
    const int* __restrict__ ssrc, const float* __restrict__ dinv,
    const float* __restrict__ b, float* __restrict__ yS, int N) {
    const int s = blockIdx.x & 7;
    const int g = (threadIdx.x & 63) >> 3;
    const int f = threadIdx.x & 7;
    const int wid = threadIdx.x >> 6;
    const int nwav = (gridDim.x >> 3) * 4;
    const float* __restrict__ hs = hsS + (size_t)s * N * 8;
    float* __restrict__ y = yS + (size_t)s * N * 8;
    const float bf = b[s * 8 + f];

    for (int d = (blockIdx.x >> 3) * 4 + wid; d < N; d += nwav) {
        int e = rowptr[d];
        const int end = rowptr[d + 1];
        float acc = (g == 0) ? hs[(size_t)d * 8 + f] : 0.f;   // self loop
        float acc2 = 0.f;
        for (; e + 16 <= end; e += 16) {
            int s1 = __builtin_nontemporal_load(ssrc + e + g);
            int s2 = __builtin_nontemporal_load(ssrc + e + 8 + g);
            acc  += hs[(size_t)s1 * 8 + f];
            acc2 += hs[(size_t)s2 * 8 + f];
        }
        for (; e + 8 <= end; e += 8) {
            int s1 = __builtin_nontemporal_load(ssrc + e + g);
            acc += hs[(size_t)s1 * 8 + f];
        }
        int idx = e + g;
        if (idx < end) {
            int s1 = __builtin_nontemporal_load(ssrc + idx);
            acc2 += hs[(size_t)s1 * 8 + f];
        }
        acc += acc2;
        acc += __shfl_xor(acc, 8);
        acc += __shfl_xor(acc, 16);
        acc += __shfl_xor(acc, 32);
        float yv = fmaf(dinv[d], acc, bf);
        if (g == 0) __builtin_nontemporal_store(yv, y + (size_t)d * 8 + f);
    }
}

// --- final layer gemm: sliced y4 -> lrelu -> W5[64,4] -> dinv scale ---------
__global__ __launch_bounds__(256) void gemm4_hs(
    const float* __restrict__ yS, const float* __restrict__ W,  // [64,4]
    const float* __restrict__ dinv, float* __restrict__ hs4, int n) {
    int i = blockIdx.x * blockDim.x + threadIdx.x;
    int stride = gridDim.x * blockDim.x;
    for (; i < n; i += stride) {
        float a0 = 0.f, a1 = 0.f, a2 = 0.f, a3 = 0.f;
#pragma unroll
        for (int s = 0; s < 8; ++s) {
            const float4* p = (const float4*)(yS + (size_t)s * n * 8 + (size_t)i * 8);
            float4 u = p[0], v = p[1];
            float e0 = u.x >= 0.f ? u.x : 0.2f * u.x;
            float e1 = u.y >= 0.f ? u.y : 0.2f * u.y;
            float e2 = u.z >= 0.f ? u.z : 0.2f * u.z;
            float e3 = u.w >= 0.f ? u.w : 0.2f * u.w;
            float e4 = v.x >= 0.f ? v.x : 0.2f * v.x;
            float e5 = v.y >= 0.f ? v.y : 0.2f * v.y;
            float e6 = v.z >= 0.f ? v.z : 0.2f * v.z;
            float e7 = v.w >= 0.f ? v.w : 0.2f * v.w;
            int k = s * 8;
            a0 = fmaf(e0, W[(k + 0) * 4 + 0], a0); a1 = fmaf(e0, W[(k + 0) * 4 + 1], a1);
            a2 = fmaf(e0, W[(k + 0) * 4 + 2], a2); a3 = fmaf(e0, W[(k + 0) * 4 + 3], a3);
            a0 = fmaf(e1, W[(k + 1) * 4 + 0], a0); a1 = fmaf(e1, W[(k + 1) * 4 + 1], a1);
            a2 = fmaf(e1, W[(k + 1) * 4 + 2], a2); a3 = fmaf(e1, W[(k + 1) * 4 + 3], a3);
            a0 = fmaf(e2, W[(k + 2) * 4 + 0], a0); a1 = fmaf(e2, W[(k + 2) * 4 + 1], a1);
            a2 = fmaf(e2, W[(k + 2) * 4 + 2], a2); a3 = fmaf(e2, W[(k + 2) * 4 + 3], a3);
            a0 = fmaf(e3, W[(k + 3) * 4 + 0], a0); a1 = fmaf(e3, W[(k + 3) * 4 + 1], a1);
            a2 = fmaf(e3, W[(k + 3) * 4 + 2], a2); a3 = fmaf(e3, W[(k + 3) * 4 + 3], a3);
            a0 = fmaf(e4, W[(k + 4) * 4 + 0], a0); a1 = fmaf(e4, W[(k + 4) * 4 + 1], a1);
            a2 = fmaf(e4, W[(k + 4) * 4 + 2], a2); a3 = fmaf(e4, W[(k + 4) * 4 + 3], a3);
            a0 = fmaf(e5, W[(k + 5) * 4 + 0], a0); a1 = fmaf(e5, W[(k + 5) * 4 + 1], a1);
            a2 = fmaf(e5, W[(k + 5) * 4 + 2], a2); a3 = fmaf(e5, W[(k + 5) * 4 + 3], a3);
            a0 = fmaf(e6, W[(k + 6) * 4 + 0], a0); a1 = fmaf(e6, W[(k + 6) * 4 + 1], a1);
            a2 = fmaf(e6, W[(k + 6) * 4 + 2], a2); a3 = fmaf(e6, W[(k + 6) * 4 + 3], a3);
            a0 = fmaf(e7, W[(k + 7) * 4 + 0], a0); a1 = fmaf(e7, W[(k + 7) * 4 + 1], a1);
            a2 = fmaf(e7, W[(k + 7) * 4 + 2], a2); a3 = fmaf(e7, W[(k + 7) * 4 + 3], a3);
        }
        float di = dinv[i];
        ((float4*)hs4)[i] = make_float4(di * a0, di * a1, di * a2, di * a3);
    }
}

// --- final aggregation over pre-scaled hs4: out = b + dinv[d]*(self + sum) --
__global__ __launch_bounds__(256) void csr_agg4(
    const float* __restrict__ hs4, const int* __restrict__ rowptr,
    const int* __restrict__ ssrc, const float* __restrict__ dinv,
    const float* __restrict__ b, float* __restrict__ out, int n) {
    int i = blockIdx.x * blockDim.x + threadIdx.x;
    int stride = gridDim.x * blockDim.x;
    float b0 = b[0], b1 = b[1], b2 = b[2], b3 = b[3];
    for (; i < n; i += stride) {
        float4 hv = ((const float4*)hs4)[i];
        float a0 = hv.x, a1 = hv.y, a2 = hv.z, a3 = hv.w;   // self loop
        int e = rowptr[i], end = rowptr[i + 1];
        for (; e < end; ++e) {
            int s = __builtin_nontemporal_load(ssrc + e);
            float4 v = ((const float4*)hs4)[s];
            a0 += v.x; a1 += v.y; a2 += v.z; a3 += v.w;
        }
        float di = dinv[i];
        ((float4*)out)[i] = make_float4(fmaf(di, a0, b0), fmaf(di, a1, b1),
                                        fmaf(di, a2, b2), fmaf(di, a3, b3));
    }
}

static inline size_t al64(size_t x) { return (x + 63) & ~(size_t)63; }

extern "C" void kernel_launch(void* const* d_in, const int* in_sizes, int n_in,
                              void* d_out, int out_size, void* d_ws, size_t ws_size,
                              hipStream_t stream) {
    const float* x  = (const float*)d_in[0];
    const int* ei   = (const int*)d_in[1];
    const float* W0 = (const float*)d_in[2];
    const float* b0 = (const float*)d_in[3];
    const float* W1 = (const float*)d_in[4];
    const float* b1 = (const float*)d_in[5];
    const float* W2 = (const float*)d_in[6];
    const float* b2 = (const float*)d_in[7];
    const float* W3 = (const float*)d_in[8];
    const float* b3 = (const float*)d_in[9];
    const float* W4 = (const float*)d_in[10];
    const float* b4 = (const float*)d_in[11];
    const float* W5 = (const float*)d_in[12];
    const float* b5 = (const float*)d_in[13];

    const int N = in_sizes[0] / 128;
    const int E = in_sizes[1] / 2;
    const int* src  = ei;       // edge_index[0] = message sources
    const int* dstp = ei + E;   // edge_index[1] = aggregation targets
    const int NB = (N + 127) >> 7;   // dst buckets of 128 ids (NB <= 1024)

    float* ws = (float*)d_ws;
    size_t off = 0;
    int*   rowptr = (int*)(ws + off);   off += al64((size_t)N + 1);
    float* dinv   = ws + off;           off += al64((size_t)N);
    int*   ssrc   = (int*)(ws + off);   off += al64((size_t)E);
    float* bufA   = ws + off;           off += (size_t)64 * N;
    float* bufB   = ws + off;

    // build temps alias into bufA (released before layer 0 writes bufA)
    int* ghist = (int*)bufA;                       // [1024]
    int* bbase = ghist + 1024;                     // [NB+1]
    int* bcur  = bbase + 1088;                     // [NB]
    int* bsrc  = (int*)(bufA + 4096);              // [E]
    unsigned char* bdl = (unsigned char*)(bsrc + E);  // [E]

    // ---- graph build (bucketed counting sort) ----
    hipMemsetAsync(ghist, 0, 1024 * sizeof(int), stream);
    bucket_hist<<<391, 256, 0, stream>>>(dstp, ghist, E, NB);
    bucket_scan<<<1, 1024, 0, stream>>>(ghist, bbase, bcur, NB, E);
    bucket_scatter<<<391, 256, 0, stream>>>(src, dstp, bcur, bsrc, bdl, E, NB);
    bucket_finalize<<<NB, 256, 0, stream>>>(bbase, bsrc, bdl, rowptr, ssrc, dinv, N, NB, E);

    // ---- layer 0: x[N,128] row-major -> hs0 sliced ----
    gemm_hs<128, false, false><<<2048, 256, 0, stream>>>(x, W0, dinv, bufA, N);
    csr_agg_sliced8<<<2048, 256, 0, stream>>>(bufA, rowptr, ssrc, dinv, b0, bufB, N);

    // ---- layers 1-4 (sliced y in, sliced hs out) ----
    const float* Ws[4] = {W1, W2, W3, W4};
    const float* bs[4] = {b1, b2, b3, b4};
    for (int l = 0; l < 4; ++l) {
        gemm_hs<64, true, true><<<2048, 256, 0, stream>>>(bufB, Ws[l], dinv, bufA, N);
        csr_agg_sliced8<<<2048, 256, 0, stream>>>(bufA, rowptr, ssrc, dinv, bs[l], bufB, N);
    }

    // ---- layer 5: sliced y4 -> hs5[N,4] -> out ----
    gemm4_hs<<<1024, 256, 0, stream>>>(bufB, W5, dinv, bufA, N);
    csr_agg4<<<2048, 256, 0, stream>>>(bufA, rowptr, ssrc, dinv, b5, (float*)d_out, N);
}

// Round 6
// 613.655 us; speedup vs baseline: 2.4721x; 2.4721x over previous
//
#include <hip/hip_runtime.h>

// ---------------------------------------------------------------------------
// 6-layer GCN. Per layer: h = lrelu?(x) @ W ; y = b + D^-1/2 (A+I) D^-1/2 h
// R5: row-major agg (wave=dst row, lane=feature, 256B wave-uniform gathers)
//     + pre-scaled hs = dinv.*h (no per-edge dinv gather)
//     + 8-edge unroll, 2 acc chains (8 gathers in flight)
//     + edge-balanced contiguous row ranges per wave (binary search rowptr)
// d_ws layout: rowptr[N+1] | dinv[N] | ssrc[E] | bufA[64N] | bufB[64N]
// Build temps alias into bufA (released before layer 0 writes bufA).
// ---------------------------------------------------------------------------

__device__ __forceinline__ float readlane_f(float v, int l) {
    union { float f; int i; } u;
    u.f = v;
    u.i = __builtin_amdgcn_readlane(u.i, l);
    return u.f;
}

// --- pass 1: coarse histogram of dst>>7 into NB buckets ---------------------
__global__ __launch_bounds__(256) void bucket_hist(const int* __restrict__ dst,
                                                   int* __restrict__ ghist,
                                                   int E, int NB) {
    __shared__ int h[1024];
    for (int i = threadIdx.x; i < NB; i += 256) h[i] = 0;
    __syncthreads();
    int i = blockIdx.x * blockDim.x + threadIdx.x;
    int stride = gridDim.x * blockDim.x;
    for (; i < E; i += stride) atomicAdd(&h[dst[i] >> 7], 1);
    __syncthreads();
    for (int j = threadIdx.x; j < NB; j += 256) {
        int c = h[j];
        if (c) atomicAdd(&ghist[j], c);
    }
}

// --- pass 2: exclusive scan of bucket counts (single block, 1024 thr) -------
__global__ void bucket_scan(const int* __restrict__ ghist, int* __restrict__ base,
                            int* __restrict__ cursor, int NB, int E) {
    int tid = threadIdx.x, lane = tid & 63, wid = tid >> 6;
    int v = (tid < NB) ? ghist[tid] : 0;
    int incl = v;
#pragma unroll
    for (int off = 1; off < 64; off <<= 1) {
        int t = __shfl_up(incl, off);
        if (lane >= off) incl += t;
    }
    __shared__ int ws[16];
    if (lane == 63) ws[wid] = incl;
    __syncthreads();
    if (tid == 0) {
        int run = 0;
        for (int i = 0; i < 16; ++i) { int t = ws[i]; ws[i] = run; run += t; }
    }
    __syncthreads();
    int excl = ws[wid] + incl - v;
    if (tid < NB) { base[tid] = excl; cursor[tid] = excl; }
    if (tid == 0) base[NB] = E;
}

// --- pass 3: scatter edges into bucket-sorted (bsrc, bdl) -------------------
__global__ __launch_bounds__(256) void bucket_scatter(
    const int* __restrict__ src, const int* __restrict__ dst,
    int* __restrict__ cursor, int* __restrict__ bsrc,
    unsigned char* __restrict__ bdl, int E, int NB) {
    __shared__ int h[1024];
    __shared__ int rb[1024];
    const int CH = 4096;
    for (int c0 = blockIdx.x * CH; c0 < E; c0 += gridDim.x * CH) {
        int cend = c0 + CH < E ? c0 + CH : E;
        for (int j = threadIdx.x; j < NB; j += 256) h[j] = 0;
        __syncthreads();
        for (int i = c0 + threadIdx.x; i < cend; i += 256)
            atomicAdd(&h[dst[i] >> 7], 1);
        __syncthreads();
        for (int j = threadIdx.x; j < NB; j += 256) {
            int c = h[j];
            rb[j] = c ? atomicAdd(&cursor[j], c) : 0;
            h[j] = 0;
        }
        __syncthreads();
        for (int i = c0 + threadIdx.x; i < cend; i += 256) {
            int d = dst[i];
            int b = d >> 7;
            int p = rb[b] + atomicAdd(&h[b], 1);
            bsrc[p] = src[i];
            bdl[p] = (unsigned char)(d & 127);
        }
        __syncthreads();
    }
}

// --- pass 4: per-bucket CSR finalize: rowptr, dinv, ssrc --------------------
__global__ __launch_bounds__(256) void bucket_finalize(
    const int* __restrict__ base, const int* __restrict__ bsrc,
    const unsigned char* __restrict__ bdl, int* __restrict__ rowptr,
    int* __restrict__ ssrc, float* __restrict__ dinv, int N, int NB, int E) {
    __shared__ int cnt[128];
    __shared__ int cur[128];
    __shared__ int w0sum;
    const int tid = threadIdx.x;
    const int lane = tid & 63;
    for (int b = blockIdx.x; b < NB; b += gridDim.x) {
        const int s = base[b], e = base[b + 1];
        const int d0 = b << 7;
        const int w = (N - d0 < 128) ? (N - d0) : 128;
        if (tid < 128) cnt[tid] = 0;
        __syncthreads();
        for (int i = s + tid; i < e; i += 256) atomicAdd(&cnt[bdl[i]], 1);
        __syncthreads();
        int v = (tid < 128) ? cnt[tid] : 0;
        int incl = v;
#pragma unroll
        for (int off = 1; off < 64; off <<= 1) {
            int t = __shfl_up(incl, off);
            if (lane >= off) incl += t;
        }
        if (tid == 63) w0sum = incl;
        __syncthreads();
        int excl = incl - v + ((tid >= 64 && tid < 128) ? w0sum : 0);
        if (tid < 128) cur[tid] = s + excl;
        if (tid < w) {
            rowptr[d0 + tid] = s + excl;
            dinv[d0 + tid] = rsqrtf((float)(v + 1));   // +1 self loop
        }
        __syncthreads();
        for (int i = s + tid; i < e; i += 256) {
            int p = atomicAdd(&cur[bdl[i]], 1);
            ssrc[p] = bsrc[i];
        }
        __syncthreads();
    }
    if (blockIdx.x == 0 && tid == 0) rowptr[N] = E;
}

// --- dense transform + dinv pre-scale (row-major in/out):
//   hs[row,l] = dinv[row] * sum_k lrelu?(in[row,k]) * W[k,l]
template <int K, bool LRELU>
__global__ __launch_bounds__(256) void gemm_hs(
    const float* __restrict__ in, const float* __restrict__ W,
    const float* __restrict__ dinv, float* __restrict__ hs, int n) {
    const int lane = threadIdx.x & 63;
    const int gw = blockIdx.x * (blockDim.x >> 6) + (threadIdx.x >> 6);
    const int nw = gridDim.x * (blockDim.x >> 6);

    float wreg[K];
#pragma unroll
    for (int k = 0; k < K; ++k) wreg[k] = W[k * 64 + lane];

    for (int row = gw; row < n; row += nw) {
        float xv0 = in[(size_t)row * K + lane];
        if (LRELU) xv0 = xv0 >= 0.f ? xv0 : 0.2f * xv0;
        float xv1 = 0.f;
        if (K == 128) xv1 = in[(size_t)row * K + 64 + lane];
        float a0 = 0.f, a1 = 0.f, a2 = 0.f, a3 = 0.f;
#pragma unroll
        for (int k = 0; k < 64; k += 4) {
            a0 = fmaf(readlane_f(xv0, k + 0), wreg[k + 0], a0);
            a1 = fmaf(readlane_f(xv0, k + 1), wreg[k + 1], a1);
            a2 = fmaf(readlane_f(xv0, k + 2), wreg[k + 2], a2);
            a3 = fmaf(readlane_f(xv0, k + 3), wreg[k + 3], a3);
        }
        if (K == 128) {
#pragma unroll
            for (int k = 0; k < 64; k += 4) {
                a0 = fmaf(readlane_f(xv1, k + 0), wreg[64 + k + 0], a0);
                a1 = fmaf(readlane_f(xv1, k + 1), wreg[64 + k + 1], a1);
                a2 = fmaf(readlane_f(xv1, k + 2), wreg[64 + k + 2], a2);
                a3 = fmaf(readlane_f(xv1, k + 3), wreg[64 + k + 3], a3);
            }
        }
        float acc = (a0 + a1) + (a2 + a3);
        hs[(size_t)row * 64 + lane] = dinv[row] * acc;
    }
}

// --- aggregation: wave = dst row (edge-balanced contiguous ranges),
//     lane = feature; y[d] = b + dinv[d] * (hs[d] + sum_e hs[src_e]) --------
__global__ __launch_bounds__(256) void csr_agg_stream(
    const float* __restrict__ hs, const int* __restrict__ rowptr,
    const int* __restrict__ ssrc, const float* __restrict__ dinv,
    const float* __restrict__ b, float* __restrict__ y,
    int N, int E, int nwaves) {
    const int lane = threadIdx.x & 63;
    const int w = blockIdx.x * (blockDim.x >> 6) + (threadIdx.x >> 6);
    if (w >= nwaves) return;
    const float bl = b[lane];

    // first row r with rowptr[r] >= t   (r in [0, N])
    auto lb = [&](long long t) {
        int lo = 0, hi = N;
        while (lo < hi) {
            int m = (lo + hi) >> 1;
            if ((long long)rowptr[m] < t) lo = m + 1; else hi = m;
        }
        return lo;
    };
    const long long q0 = (long long)w * E / nwaves;
    const long long q1 = (long long)(w + 1) * E / nwaves;
    int r0 = lb(q0);
    int r1 = (w == nwaves - 1) ? N : lb(q1);

    for (int d = r0; d < r1; ++d) {
        int e = __builtin_amdgcn_readfirstlane(rowptr[d]);
        const int end = __builtin_amdgcn_readfirstlane(rowptr[d + 1]);
        float acc0 = hs[(size_t)d * 64 + lane];   // self loop (pre-scaled)
        float acc1 = 0.f;
        for (; e + 8 <= end; e += 8) {
            int s0 = ssrc[e + 0], s1 = ssrc[e + 1];
            int s2 = ssrc[e + 2], s3 = ssrc[e + 3];
            int s4 = ssrc[e + 4], s5 = ssrc[e + 5];
            int s6 = ssrc[e + 6], s7 = ssrc[e + 7];
            float v0 = hs[(size_t)s0 * 64 + lane];
            float v1 = hs[(size_t)s1 * 64 + lane];
            float v2 = hs[(size_t)s2 * 64 + lane];
            float v3 = hs[(size_t)s3 * 64 + lane];
            float v4 = hs[(size_t)s4 * 64 + lane];
            float v5 = hs[(size_t)s5 * 64 + lane];
            float v6 = hs[(size_t)s6 * 64 + lane];
            float v7 = hs[(size_t)s7 * 64 + lane];
            acc0 += v0 + v2;
            acc1 += v1 + v3;
            acc0 += v4 + v6;
            acc1 += v5 + v7;
        }
        for (; e < end; ++e) {
            int s = ssrc[e];
            acc0 += hs[(size_t)s * 64 + lane];
        }
        y[(size_t)d * 64 + lane] = fmaf(dinv[d], acc0 + acc1, bl);
    }
}

// --- final layer gemm: row-major y -> lrelu -> W5[64,4] -> dinv scale -------
__global__ __launch_bounds__(256) void gemm4_hs(
    const float* __restrict__ y, const float* __restrict__ W,  // [64,4]
    const float* __restrict__ dinv, float* __restrict__ hs4, int n) {
    int i = blockIdx.x * blockDim.x + threadIdx.x;
    int stride = gridDim.x * blockDim.x;
    for (; i < n; i += stride) {
        const float4* xr = (const float4*)(y + (size_t)i * 64);
        float a0 = 0.f, a1 = 0.f, a2 = 0.f, a3 = 0.f;
#pragma unroll
        for (int k4 = 0; k4 < 16; ++k4) {
            float4 xv = xr[k4];
            float e0 = xv.x >= 0.f ? xv.x : 0.2f * xv.x;
            float e1 = xv.y >= 0.f ? xv.y : 0.2f * xv.y;
            float e2 = xv.z >= 0.f ? xv.z : 0.2f * xv.z;
            float e3 = xv.w >= 0.f ? xv.w : 0.2f * xv.w;
            int k = k4 * 4;
            a0 = fmaf(e0, W[(k + 0) * 4 + 0], a0); a1 = fmaf(e0, W[(k + 0) * 4 + 1], a1);
            a2 = fmaf(e0, W[(k + 0) * 4 + 2], a2); a3 = fmaf(e0, W[(k + 0) * 4 + 3], a3);
            a0 = fmaf(e1, W[(k + 1) * 4 + 0], a0); a1 = fmaf(e1, W[(k + 1) * 4 + 1], a1);
            a2 = fmaf(e1, W[(k + 1) * 4 + 2], a2); a3 = fmaf(e1, W[(k + 1) * 4 + 3], a3);
            a0 = fmaf(e2, W[(k + 2) * 4 + 0], a0); a1 = fmaf(e2, W[(k + 2) * 4 + 1], a1);
            a2 = fmaf(e2, W[(k + 2) * 4 + 2], a2); a3 = fmaf(e2, W[(k + 2) * 4 + 3], a3);
            a0 = fmaf(e3, W[(k + 3) * 4 + 0], a0); a1 = fmaf(e3, W[(k + 3) * 4 + 1], a1);
            a2 = fmaf(e3, W[(k + 3) * 4 + 2], a2); a3 = fmaf(e3, W[(k + 3) * 4 + 3], a3);
        }
        float di = dinv[i];
        ((float4*)hs4)[i] = make_float4(di * a0, di * a1, di * a2, di * a3);
    }
}

// --- final aggregation over pre-scaled hs4: out = b + dinv[d]*(self + sum) --
__global__ __launch_bounds__(256) void csr_agg4(
    const float* __restrict__ hs4, const int* __restrict__ rowptr,
    const int* __restrict__ ssrc, const float* __restrict__ dinv,
    const float* __restrict__ b, float* __restrict__ out, int n) {
    int i = blockIdx.x * blockDim.x + threadIdx.x;
    int stride = gridDim.x * blockDim.x;
    float b0 = b[0], b1 = b[1], b2 = b[2], b3 = b[3];
    for (; i < n; i += stride) {
        float4 hv = ((const float4*)hs4)[i];
        float a0 = hv.x, a1 = hv.y, a2 = hv.z, a3 = hv.w;   // self loop
        int e = rowptr[i], end = rowptr[i + 1];
        for (; e < end; ++e) {
            int s = ssrc[e];
            float4 v = ((const float4*)hs4)[s];
            a0 += v.x; a1 += v.y; a2 += v.z; a3 += v.w;
        }
        float di = dinv[i];
        ((float4*)out)[i] = make_float4(fmaf(di, a0, b0), fmaf(di, a1, b1),
                                        fmaf(di, a2, b2), fmaf(di, a3, b3));
    }
}

static inline size_t al64(size_t x) { return (x + 63) & ~(size_t)63; }

extern "C" void kernel_launch(void* const* d_in, const int* in_sizes, int n_in,
                              void* d_out, int out_size, void* d_ws, size_t ws_size,
                              hipStream_t stream) {
    const float* x  = (const float*)d_in[0];
    const int* ei   = (const int*)d_in[1];
    const float* W0 = (const float*)d_in[2];
    const float* b0 = (const float*)d_in[3];
    const float* W1 = (const float*)d_in[4];
    const float* b1 = (const float*)d_in[5];
    const float* W2 = (const float*)d_in[6];
    const float* b2 = (const float*)d_in[7];
    const float* W3 = (const float*)d_in[8];
    const float* b3 = (const float*)d_in[9];
    const float* W4 = (const float*)d_in[10];
    const float* b4 = (const float*)d_in[11];
    const float* W5 = (const float*)d_in[12];
    const float* b5 = (const float*)d_in[13];

    const int N = in_sizes[0] / 128;
    const int E = in_sizes[1] / 2;
    const int* src  = ei;       // edge_index[0] = message sources
    const int* dstp = ei + E;   // edge_index[1] = aggregation targets
    const int NB = (N + 127) >> 7;   // dst buckets of 128 ids (NB <= 1024)

    float* ws = (float*)d_ws;
    size_t off = 0;
    int*   rowptr = (int*)(ws + off);   off += al64((size_t)N + 1);
    float* dinv   = ws + off;           off += al64((size_t)N);
    int*   ssrc   = (int*)(ws + off);   off += al64((size_t)E);
    float* bufA   = ws + off;           off += (size_t)64 * N;
    float* bufB   = ws + off;

    // build temps alias into bufA (released before layer 0 writes bufA)
    int* ghist = (int*)bufA;                       // [1024]
    int* bbase = ghist + 1024;                     // [NB+1]
    int* bcur  = bbase + 1088;                     // [NB]
    int* bsrc  = (int*)(bufA + 4096);              // [E]
    unsigned char* bdl = (unsigned char*)(bsrc + E);  // [E]

    // ---- graph build (bucketed counting sort) ----
    hipMemsetAsync(ghist, 0, 1024 * sizeof(int), stream);
    bucket_hist<<<391, 256, 0, stream>>>(dstp, ghist, E, NB);
    bucket_scan<<<1, 1024, 0, stream>>>(ghist, bbase, bcur, NB, E);
    bucket_scatter<<<391, 256, 0, stream>>>(src, dstp, bcur, bsrc, bdl, E, NB);
    bucket_finalize<<<NB, 256, 0, stream>>>(bbase, bsrc, bdl, rowptr, ssrc, dinv, N, NB, E);

    const int AGG_BLOCKS = 2048;
    const int NWAVES = AGG_BLOCKS * 4;

    // ---- layer 0: x[N,128] -> hs (row-major) ----
    gemm_hs<128, false><<<2048, 256, 0, stream>>>(x, W0, dinv, bufA, N);
    csr_agg_stream<<<AGG_BLOCKS, 256, 0, stream>>>(bufA, rowptr, ssrc, dinv, b0, bufB, N, E, NWAVES);

    // ---- layers 1-4 ----
    const float* Ws[4] = {W1, W2, W3, W4};
    const float* bs[4] = {b1, b2, b3, b4};
    for (int l = 0; l < 4; ++l) {
        gemm_hs<64, true><<<2048, 256, 0, stream>>>(bufB, Ws[l], dinv, bufA, N);
        csr_agg_stream<<<AGG_BLOCKS, 256, 0, stream>>>(bufA, rowptr, ssrc, dinv, bs[l], bufB, N, E, NWAVES);
    }

    // ---- layer 5: y -> hs4[N,4] -> out ----
    gemm4_hs<<<1024, 256, 0, stream>>>(bufB, W5, dinv, bufA, N);
    csr_agg4<<<512, 256, 0, stream>>>(bufA, rowptr, ssrc, dinv, b5, (float*)d_out, N);
}